// Round 3
// baseline (474.905 us; speedup 1.0000x reference)
//
#include <hip/hip_runtime.h>
#include <hip/hip_bf16.h>

typedef __bf16 bf16;
typedef __bf16 bf16x8 __attribute__((ext_vector_type(8)));
typedef float f32x16 __attribute__((ext_vector_type(16)));
typedef float f32x4 __attribute__((ext_vector_type(4)));
typedef unsigned int u32x4 __attribute__((ext_vector_type(4)));

#define NB 4
#define NC 512
#define NN 4096

// log2(e) / sqrt(512): exp(s/sqrt(512)) == exp2(s * EXP2_SCALE)
static constexpr float EXP2_SCALE = 0.063763926f;

static __device__ __forceinline__ unsigned pack_bf2(float a, float b){
  unsigned short ux = __builtin_bit_cast(unsigned short, (bf16)a);
  unsigned short uy = __builtin_bit_cast(unsigned short, (bf16)b);
  return (unsigned)ux | ((unsigned)uy << 16);
}

union FragU { unsigned u[4]; bf16x8 v; };

static __device__ __forceinline__ f32x16 zero16(){
  f32x16 z;
#pragma unroll
  for(int i=0;i<16;i++) z[i] = 0.0f;
  return z;
}

// ---- K1a: wv [512][512] f32 -> wvL[cin/16][co][cin%16] bf16 (A-frag layout)
__global__ __launch_bounds__(256) void k_wv_cvt(const float* __restrict__ wv,
                                                bf16* __restrict__ wvL){
  int t  = blockIdx.x * 256 + threadIdx.x;   // 16384 threads
  int cg = t & 31;
  int co = t >> 5;
  const float* s = wv + (size_t)co * NC + cg * 16;
  unsigned w[8];
#pragma unroll
  for(int j=0;j<8;j++) w[j] = pack_bf2(s[2*j], s[2*j+1]);
  u32x4* d = (u32x4*)((char*)wvL + (size_t)(cg * NC + co) * 32);
  d[0] = (u32x4){w[0],w[1],w[2],w[3]};
  d[1] = (u32x4){w[4],w[5],w[6],w[7]};
}

// ---- K1b: v [B][C][N] f32 -> vL[b][c/16][n][c%16] bf16 (B-frag layout)
__global__ __launch_bounds__(256) void k_v_cvt(const float* __restrict__ v,
                                               bf16* __restrict__ vL){
  int bid = blockIdx.x;            // 2048 = B*32*16
  int n  = (bid & 15) * 256 + threadIdx.x;
  int cg = (bid >> 4) & 31;
  int b  = bid >> 9;
  const float* s = v + ((size_t)(b * NC + cg * 16)) * NN + n;
  unsigned w[8];
#pragma unroll
  for(int j=0;j<8;j++) w[j] = pack_bf2(s[(size_t)(2*j)*NN], s[(size_t)(2*j+1)*NN]);
  u32x4* d = (u32x4*)((char*)vL + ((size_t)(b*32 + cg) * NN + n) * 32);
  d[0] = (u32x4){w[0],w[1],w[2],w[3]};
  d[1] = (u32x4){w[4],w[5],w[6],w[7]};
}

// ---- K2: q,k projections -> Pq, Pk bf16 [B][N][16]
__global__ __launch_bounds__(256) void k_proj_qk(
    const float* __restrict__ q, const float* __restrict__ kin,
    const float* __restrict__ wq, const float* __restrict__ bq,
    const float* __restrict__ wk, const float* __restrict__ bk,
    bf16* __restrict__ Pq, bf16* __restrict__ Pk){
  __shared__ float red[4][64][20];           // +pad: spreads banks
  int b  = blockIdx.x >> 6;
  int n0 = (blockIdx.x & 63) * 64;
  int w  = threadIdx.x >> 6;
  int lane = threadIdx.x & 63;
  const float* src = (w < 2) ? q  : kin;
  const float* wt  = (w < 2) ? wq : wk;
  int c0 = (w & 1) * 256;
  float acc[16];
#pragma unroll
  for(int o=0;o<16;o++) acc[o] = 0.0f;
  const float* sp = src + ((size_t)(b * NC + c0)) * NN + n0 + lane;
  for(int c=0;c<256;c++){
    float x = sp[(size_t)c * NN];            // coalesced across lanes
#pragma unroll
    for(int o=0;o<16;o++) acc[o] += wt[o * NC + c0 + c] * x;  // uniform -> s_load
  }
#pragma unroll
  for(int o4=0;o4<4;o4++)
    *(f32x4*)&red[w][lane][o4*4] = (f32x4){acc[o4*4],acc[o4*4+1],acc[o4*4+2],acc[o4*4+3]};
  __syncthreads();
  if(threadIdx.x < 128){
    int isk = threadIdx.x >> 6;              // 0 -> q, 1 -> k
    int tok = threadIdx.x & 63;
    const float* bias = isk ? bk : bq;
    bf16* dst = isk ? Pk : Pq;
    int wb = isk * 2;
    unsigned wd[8];
#pragma unroll
    for(int t=0;t<8;t++){
      float a0 = red[wb][tok][2*t]   + red[wb+1][tok][2*t]   + bias[2*t];
      float a1 = red[wb][tok][2*t+1] + red[wb+1][tok][2*t+1] + bias[2*t+1];
      wd[t] = pack_bf2(a0, a1);
    }
    u32x4* d = (u32x4*)((char*)dst + ((size_t)(b * NN + n0 + tok)) * 32);
    d[0] = (u32x4){wd[0],wd[1],wd[2],wd[3]};
    d[1] = (u32x4){wd[4],wd[5],wd[6],wd[7]};
  }
}

// ---- K3: proj_v GEMM (bf16 MFMA): Pv = wv @ v + bv -> PvL[b][j/16][c][j%16]
__global__ __launch_bounds__(256) void k_proj_v(
    const bf16* __restrict__ wvL, const bf16* __restrict__ vL,
    const float* __restrict__ bv, bf16* __restrict__ PvL){
  int bid = blockIdx.x;                 // 2048 = B * 8 * 64
  int nt  = bid & 63;
  int cot = (bid >> 6) & 7;
  int b   = bid >> 9;
  int w    = threadIdx.x >> 6;
  int lane = threadIdx.x & 63;
  int l31 = lane & 31, h = lane >> 5;
  int co0 = cot * 64 + (w >> 1) * 32;
  int n0  = nt * 64 + (w & 1) * 32;
  const char* ap = (const char*)wvL + (size_t)(co0 + l31) * 32 + h * 16;
  const char* bp = (const char*)vL + ((size_t)(b * 32) * NN + n0 + l31) * 32 + h * 16;
  f32x16 acc = zero16();
  for(int kc=0;kc<32;kc++){
    bf16x8 af  = *(const bf16x8*)(ap + (size_t)kc * NC * 32);
    bf16x8 bfr = *(const bf16x8*)(bp + (size_t)kc * NN * 32);
    acc = __builtin_amdgcn_mfma_f32_32x32x16_bf16(af, bfr, acc, 0, 0, 0);
  }
  int j = n0 + l31;
  char* dbase = (char*)PvL + ((size_t)(b*256 + (j >> 4)) * NC) * 32 + (j & 15) * 2;
#pragma unroll
  for(int r=0;r<16;r++){
    int row = (r & 3) + 8 * (r >> 2) + 4 * h;   // C/D layout (m74/m101)
    int co = co0 + row;
    float val = acc[r] + bv[co];
    *(bf16*)(dbase + (size_t)co * 32) = (bf16)val;
  }
}

// ---- K4: flash attention (no-max softmax, valid since |logit| <~ 1.1) + residual v
__global__ __launch_bounds__(512, 2) void k_attn(
    const bf16* __restrict__ Pq, const bf16* __restrict__ Pk,
    const bf16* __restrict__ PvL, const float* __restrict__ vin,
    float* __restrict__ out){
  int b  = blockIdx.x >> 6;
  int i0 = (blockIdx.x & 63) * 64;
  int w    = threadIdx.x >> 6;
  int lane = threadIdx.x & 63;
  int l31 = lane & 31, h = lane >> 5;
  int i0w = i0 + (w >> 2) * 32;     // 2 i-subtiles
  int c0w = (w & 3) * 128;          // 4 c-chunks

  bf16x8 qf = *(const bf16x8*)((const char*)Pq + ((size_t)(b * NN + i0w + l31)) * 32 + h * 16);

  f32x16 acc[4];
  acc[0]=zero16(); acc[1]=zero16(); acc[2]=zero16(); acc[3]=zero16();
  float lsum = 0.0f;

  const char* pkbase = (const char*)Pk  + ((size_t)b * NN) * 32 + h * 16;
  const char* pvbase = (const char*)PvL + ((size_t)(b * 256) * NC) * 32 + h * 16;

  for(int jt=0;jt<128;jt++){
    // S^T tile [32j x 32i] = mfma(K, Q): puts P row i = lane&31 (lane-local)
    bf16x8 kf = *(const bf16x8*)(pkbase + (size_t)(jt * 32 + l31) * 32);
    f32x16 s = __builtin_amdgcn_mfma_f32_32x32x16_bf16(kf, qf, zero16(), 0, 0, 0);
    float p[16];
#pragma unroll
    for(int r=0;r<16;r++){
      p[r] = exp2f(s[r] * EXP2_SCALE);   // == exp(s/sqrt(512)); v_exp_f32 is 2^x
      lsum += p[r];
    }
    // pack to bf16 pairs; j(r,h) = (r&3) + 8*(r>>2) + 4h
    unsigned qw[8], ew[8];
#pragma unroll
    for(int t=0;t<8;t++) qw[t] = pack_bf2(p[2*t], p[2*t+1]);
#pragma unroll
    for(int t=0;t<8;t++) ew[t] = (unsigned)__shfl_xor((int)qw[t], 32);
    // build PV A-frags: k-step0 j=0..15, k-step1 j=16..31
    FragU pa0, pa1;
    pa0.u[0] = h ? ew[2] : qw[0];
    pa0.u[1] = h ? ew[3] : qw[1];
    pa0.u[2] = h ? qw[2] : ew[0];
    pa0.u[3] = h ? qw[3] : ew[1];
    pa1.u[0] = h ? ew[6] : qw[4];
    pa1.u[1] = h ? ew[7] : qw[5];
    pa1.u[2] = h ? qw[6] : ew[4];
    pa1.u[3] = h ? qw[7] : ew[5];
#pragma unroll
    for(int ct=0;ct<4;ct++){
      const char* pvp = pvbase + ((size_t)(jt * 2) * NC + c0w + ct * 32 + l31) * 32;
      bf16x8 v0 = *(const bf16x8*)pvp;                      // k-step0 (j0..j0+15)
      bf16x8 v1 = *(const bf16x8*)(pvp + (size_t)NC * 32);  // k-step1
      acc[ct] = __builtin_amdgcn_mfma_f32_32x32x16_bf16(pa0.v, v0, acc[ct], 0, 0, 0);
      acc[ct] = __builtin_amdgcn_mfma_f32_32x32x16_bf16(pa1.v, v1, acc[ct], 0, 0, 0);
    }
  }
  // denominator: lane l31 holds partial sum for row i = i0w + l31 (its j-half)
  lsum += __shfl_xor(lsum, 32);
  float rl = 1.0f / lsum;
  float rlr[16];
#pragma unroll
  for(int r=0;r<16;r++){
    int row = (r & 3) + 8 * (r >> 2) + 4 * h;
    rlr[r] = __shfl(rl, row);
  }
  // epilogue: out[b][c][i] = acc/l + v  (regs r=4g..4g+3 are 4 consecutive i)
#pragma unroll
  for(int ct=0;ct<4;ct++){
    int c = c0w + ct * 32 + l31;
    const float* vp = vin + ((size_t)(b * NC + c)) * NN + i0w;
    float* op = out + ((size_t)(b * NC + c)) * NN + i0w;
#pragma unroll
    for(int g=0;g<4;g++){
      int ib = 8 * g + 4 * h;
      f32x4 vv = *(const f32x4*)(vp + ib);
      f32x4 ov;
#pragma unroll
      for(int e=0;e<4;e++) ov[e] = acc[ct][4*g+e] * rlr[4*g+e] + vv[e];
      *(f32x4*)(op + ib) = ov;
    }
  }
}

extern "C" void kernel_launch(void* const* d_in, const int* in_sizes, int n_in,
                              void* d_out, int out_size, void* d_ws, size_t ws_size,
                              hipStream_t stream) {
  const float* q  = (const float*)d_in[0];
  const float* k  = (const float*)d_in[1];
  const float* v  = (const float*)d_in[2];
  const float* wq = (const float*)d_in[3];
  const float* bq = (const float*)d_in[4];
  const float* wk = (const float*)d_in[5];
  const float* bk = (const float*)d_in[6];
  const float* wv = (const float*)d_in[7];
  const float* bv = (const float*)d_in[8];
  float* out = (float*)d_out;
  char* ws = (char*)d_ws;

  // workspace layout (bytes): Pq 512K | Pk 512K | wvL 512K | vL 16M | PvL 16M
  bf16* Pq  = (bf16*)(ws);
  bf16* Pk  = (bf16*)(ws + (1u<<19));
  bf16* wvL = (bf16*)(ws + (2u<<19));
  bf16* vL  = (bf16*)(ws + (3u<<19));
  bf16* PvL = (bf16*)(ws + (3u<<19) + (16u<<20));

  k_wv_cvt <<<64,   256, 0, stream>>>(wv, wvL);
  k_v_cvt  <<<2048, 256, 0, stream>>>(v, vL);
  k_proj_qk<<<256,  256, 0, stream>>>(q, k, wq, bq, wk, bk, Pq, Pk);
  k_proj_v <<<2048, 256, 0, stream>>>(wvL, vL, bv, PvL);
  k_attn   <<<256,  512, 0, stream>>>(Pq, Pk, PvL, v, out);
}

// Round 4
// 341.550 us; speedup vs baseline: 1.3904x; 1.3904x over previous
//
#include <hip/hip_runtime.h>
#include <hip/hip_bf16.h>

typedef __bf16 bf16;
typedef __bf16 bf16x8 __attribute__((ext_vector_type(8)));
typedef float f32x16 __attribute__((ext_vector_type(16)));
typedef float f32x4 __attribute__((ext_vector_type(4)));
typedef unsigned int u32x4 __attribute__((ext_vector_type(4)));

#define NB 4
#define NC 512
#define NN 4096

// log2(e) / sqrt(512): exp(s/sqrt(512)) == exp2(s * EXP2_SCALE)
static constexpr float EXP2_SCALE = 0.063763926f;

static __device__ __forceinline__ unsigned pack_bf2(float a, float b){
  unsigned short ux = __builtin_bit_cast(unsigned short, (bf16)a);
  unsigned short uy = __builtin_bit_cast(unsigned short, (bf16)b);
  return (unsigned)ux | ((unsigned)uy << 16);
}

union FragU { unsigned u[4]; bf16x8 v; };

static __device__ __forceinline__ f32x16 zero16(){
  f32x16 z;
#pragma unroll
  for(int i=0;i<16;i++) z[i] = 0.0f;
  return z;
}

// ---- K1a: wv [512][512] f32 -> wvL[cin/16][co][cin%16] bf16 (A-frag layout)
__global__ __launch_bounds__(256) void k_wv_cvt(const float* __restrict__ wv,
                                                bf16* __restrict__ wvL){
  int t  = blockIdx.x * 256 + threadIdx.x;   // 16384 threads
  int cg = t & 31;
  int co = t >> 5;
  const float* s = wv + (size_t)co * NC + cg * 16;
  unsigned w[8];
#pragma unroll
  for(int j=0;j<8;j++) w[j] = pack_bf2(s[2*j], s[2*j+1]);
  u32x4* d = (u32x4*)((char*)wvL + (size_t)(cg * NC + co) * 32);
  d[0] = (u32x4){w[0],w[1],w[2],w[3]};
  d[1] = (u32x4){w[4],w[5],w[6],w[7]};
}

// ---- K1b: v [B][C][N] f32 -> vL[b][c/16][n][c%16] bf16 (B-frag layout)
__global__ __launch_bounds__(256) void k_v_cvt(const float* __restrict__ v,
                                               bf16* __restrict__ vL){
  int bid = blockIdx.x;            // 2048 = B*32*16
  int n  = (bid & 15) * 256 + threadIdx.x;
  int cg = (bid >> 4) & 31;
  int b  = bid >> 9;
  const float* s = v + ((size_t)(b * NC + cg * 16)) * NN + n;
  unsigned w[8];
#pragma unroll
  for(int j=0;j<8;j++) w[j] = pack_bf2(s[(size_t)(2*j)*NN], s[(size_t)(2*j+1)*NN]);
  u32x4* d = (u32x4*)((char*)vL + ((size_t)(b*32 + cg) * NN + n) * 32);
  d[0] = (u32x4){w[0],w[1],w[2],w[3]};
  d[1] = (u32x4){w[4],w[5],w[6],w[7]};
}

// ---- K2: q,k projections -> Pq, Pk bf16 [B][N][16]
__global__ __launch_bounds__(256) void k_proj_qk(
    const float* __restrict__ q, const float* __restrict__ kin,
    const float* __restrict__ wq, const float* __restrict__ bq,
    const float* __restrict__ wk, const float* __restrict__ bk,
    bf16* __restrict__ Pq, bf16* __restrict__ Pk){
  __shared__ float red[4][64][20];           // +pad: spreads banks
  int b  = blockIdx.x >> 6;
  int n0 = (blockIdx.x & 63) * 64;
  int w  = threadIdx.x >> 6;
  int lane = threadIdx.x & 63;
  const float* src = (w < 2) ? q  : kin;
  const float* wt  = (w < 2) ? wq : wk;
  int c0 = (w & 1) * 256;
  float acc[16];
#pragma unroll
  for(int o=0;o<16;o++) acc[o] = 0.0f;
  const float* sp = src + ((size_t)(b * NC + c0)) * NN + n0 + lane;
  for(int c=0;c<256;c++){
    float x = sp[(size_t)c * NN];            // coalesced across lanes
#pragma unroll
    for(int o=0;o<16;o++) acc[o] += wt[o * NC + c0 + c] * x;  // uniform -> s_load
  }
#pragma unroll
  for(int o4=0;o4<4;o4++)
    *(f32x4*)&red[w][lane][o4*4] = (f32x4){acc[o4*4],acc[o4*4+1],acc[o4*4+2],acc[o4*4+3]};
  __syncthreads();
  if(threadIdx.x < 128){
    int isk = threadIdx.x >> 6;              // 0 -> q, 1 -> k
    int tok = threadIdx.x & 63;
    const float* bias = isk ? bk : bq;
    bf16* dst = isk ? Pk : Pq;
    int wb = isk * 2;
    unsigned wd[8];
#pragma unroll
    for(int t=0;t<8;t++){
      float a0 = red[wb][tok][2*t]   + red[wb+1][tok][2*t]   + bias[2*t];
      float a1 = red[wb][tok][2*t+1] + red[wb+1][tok][2*t+1] + bias[2*t+1];
      wd[t] = pack_bf2(a0, a1);
    }
    u32x4* d = (u32x4*)((char*)dst + ((size_t)(b * NN + n0 + tok)) * 32);
    d[0] = (u32x4){wd[0],wd[1],wd[2],wd[3]};
    d[1] = (u32x4){wd[4],wd[5],wd[6],wd[7]};
  }
}

// ---- K3: proj_v GEMM (bf16 MFMA): Pv = wv @ v + bv -> PvL[b][j/16][c][j%16]
__global__ __launch_bounds__(256) void k_proj_v(
    const bf16* __restrict__ wvL, const bf16* __restrict__ vL,
    const float* __restrict__ bv, bf16* __restrict__ PvL){
  int bid = blockIdx.x;                 // 2048 = B * 8 * 64
  int nt  = bid & 63;
  int cot = (bid >> 6) & 7;
  int b   = bid >> 9;
  int w    = threadIdx.x >> 6;
  int lane = threadIdx.x & 63;
  int l31 = lane & 31, h = lane >> 5;
  int co0 = cot * 64 + (w >> 1) * 32;
  int n0  = nt * 64 + (w & 1) * 32;
  const char* ap = (const char*)wvL + (size_t)(co0 + l31) * 32 + h * 16;
  const char* bp = (const char*)vL + ((size_t)(b * 32) * NN + n0 + l31) * 32 + h * 16;
  f32x16 acc = zero16();
  for(int kc=0;kc<32;kc++){
    bf16x8 af  = *(const bf16x8*)(ap + (size_t)kc * NC * 32);
    bf16x8 bfr = *(const bf16x8*)(bp + (size_t)kc * NN * 32);
    acc = __builtin_amdgcn_mfma_f32_32x32x16_bf16(af, bfr, acc, 0, 0, 0);
  }
  int j = n0 + l31;
  char* dbase = (char*)PvL + ((size_t)(b*256 + (j >> 4)) * NC) * 32 + (j & 15) * 2;
#pragma unroll
  for(int r=0;r<16;r++){
    int row = (r & 3) + 8 * (r >> 2) + 4 * h;   // C/D layout (m74/m101)
    int co = co0 + row;
    float val = acc[r] + bv[co];
    *(bf16*)(dbase + (size_t)co * 32) = (bf16)val;
  }
}

// ---- K4 v2: flash attention, j-parallel P computed ONCE and shared via LDS.
// Block = 32 i-rows x 512 c, 8 waves. Per 256-j J-block: wave w computes P for
// jt = J*8+w (QK^T, exp, pack -> A-frags) into LDS (double-buffered, 1 barrier);
// then each wave runs PV for its 64-c chunk over all 8 shared jt tiles.
// No-max softmax stays valid (|logit| <~ 1.1); denominators reduce via LDS.
__global__ __launch_bounds__(512, 4) void k_attn(
    const bf16* __restrict__ Pq, const bf16* __restrict__ Pk,
    const bf16* __restrict__ PvL, const float* __restrict__ vin,
    float* __restrict__ out){
  __shared__ __attribute__((aligned(16))) unsigned P_lds[2][8][64][8]; // [dbuf][jt][lane][frag]
  __shared__ float lsum_lds[8][64];
  int b  = blockIdx.x >> 7;
  int i0 = (blockIdx.x & 127) * 32;
  int w    = threadIdx.x >> 6;
  int lane = threadIdx.x & 63;
  int l31 = lane & 31, h = lane >> 5;
  int c0 = w * 64;                       // this wave's channel chunk (phase 2)

  bf16x8 qf = *(const bf16x8*)((const char*)Pq + ((size_t)(b * NN + i0 + l31)) * 32 + h * 16);

  f32x16 acc0 = zero16(), acc1 = zero16();
  float lsum = 0.0f;

  const char* pkbase = (const char*)Pk  + ((size_t)b * NN) * 32 + h * 16;
  const char* pvbase = (const char*)PvL + ((size_t)(b * 256) * NC) * 32 + h * 16;

  for(int J=0;J<16;J++){
    int buf = J & 1;
    // ---- phase 1: this wave's jt = J*8 + w -> P A-frags to LDS
    {
      bf16x8 kf = *(const bf16x8*)(pkbase + (size_t)((J*8 + w)*32 + l31) * 32);
      f32x16 s = __builtin_amdgcn_mfma_f32_32x32x16_bf16(kf, qf, zero16(), 0, 0, 0);
      float p[16];
#pragma unroll
      for(int r=0;r<16;r++){ p[r] = exp2f(s[r] * EXP2_SCALE); lsum += p[r]; }
      unsigned qw[8], ew[8];
#pragma unroll
      for(int t=0;t<8;t++) qw[t] = pack_bf2(p[2*t], p[2*t+1]);
#pragma unroll
      for(int t=0;t<8;t++) ew[t] = (unsigned)__shfl_xor((int)qw[t], 32);
      u32x4 pa0 = h ? (u32x4){ew[2],ew[3],qw[2],qw[3]} : (u32x4){qw[0],qw[1],ew[0],ew[1]};
      u32x4 pa1 = h ? (u32x4){ew[6],ew[7],qw[6],qw[7]} : (u32x4){qw[4],qw[5],ew[4],ew[5]};
      u32x4* dst = (u32x4*)&P_lds[buf][w][lane][0];
      dst[0] = pa0;
      dst[1] = pa1;
    }
    __syncthreads();
    // ---- phase 2: PV over the 8 shared jt tiles, this wave's 64 channels
#pragma unroll
    for(int t=0;t<8;t++){
      FragU pa0, pa1;
      const u32x4* src = (const u32x4*)&P_lds[buf][t][lane][0];
      *(u32x4*)pa0.u = src[0];
      *(u32x4*)pa1.u = src[1];
      const char* pvp = pvbase + (((size_t)(J*8 + t) * 2) * NC + c0 + l31) * 32;
      bf16x8 v00 = *(const bf16x8*)(pvp);                         // kstep0, csub0
      bf16x8 v10 = *(const bf16x8*)(pvp + (size_t)NC * 32);       // kstep1, csub0
      bf16x8 v01 = *(const bf16x8*)(pvp + 1024);                  // kstep0, csub1
      bf16x8 v11 = *(const bf16x8*)(pvp + (size_t)NC * 32 + 1024);// kstep1, csub1
      acc0 = __builtin_amdgcn_mfma_f32_32x32x16_bf16(pa0.v, v00, acc0, 0, 0, 0);
      acc0 = __builtin_amdgcn_mfma_f32_32x32x16_bf16(pa1.v, v10, acc0, 0, 0, 0);
      acc1 = __builtin_amdgcn_mfma_f32_32x32x16_bf16(pa0.v, v01, acc1, 0, 0, 0);
      acc1 = __builtin_amdgcn_mfma_f32_32x32x16_bf16(pa1.v, v11, acc1, 0, 0, 0);
    }
  }
  // ---- denominator: cross-wave reduce (no-max softmax is plain summation)
  lsum_lds[w][lane] = lsum;
  __syncthreads();
  float rowsum = 0.0f;
#pragma unroll
  for(int ww=0;ww<8;ww++) rowsum += lsum_lds[ww][l31] + lsum_lds[ww][l31 + 32];
  float rl = 1.0f / rowsum;
  float rlr[16];
#pragma unroll
  for(int r=0;r<16;r++) rlr[r] = __shfl(rl, (r & 3) + 8 * (r >> 2) + 4 * h);
  // ---- epilogue: out[b][c][i] = acc/l + v
#pragma unroll
  for(int cs=0;cs<2;cs++){
    f32x16 a = cs ? acc1 : acc0;
    int c = c0 + cs * 32 + l31;
    const float* vp = vin + ((size_t)(b * NC + c)) * NN + i0;
    float* op = out + ((size_t)(b * NC + c)) * NN + i0;
#pragma unroll
    for(int g=0;g<4;g++){
      int ib = 8 * g + 4 * h;
      f32x4 vv = *(const f32x4*)(vp + ib);
      f32x4 ov;
#pragma unroll
      for(int e=0;e<4;e++) ov[e] = a[4*g+e] * rlr[4*g+e] + vv[e];
      *(f32x4*)(op + ib) = ov;
    }
  }
}

extern "C" void kernel_launch(void* const* d_in, const int* in_sizes, int n_in,
                              void* d_out, int out_size, void* d_ws, size_t ws_size,
                              hipStream_t stream) {
  const float* q  = (const float*)d_in[0];
  const float* k  = (const float*)d_in[1];
  const float* v  = (const float*)d_in[2];
  const float* wq = (const float*)d_in[3];
  const float* bq = (const float*)d_in[4];
  const float* wk = (const float*)d_in[5];
  const float* bk = (const float*)d_in[6];
  const float* wv = (const float*)d_in[7];
  const float* bv = (const float*)d_in[8];
  float* out = (float*)d_out;
  char* ws = (char*)d_ws;

  // workspace layout (bytes): Pq 512K | Pk 512K | wvL 512K | vL 16M | PvL 16M
  bf16* Pq  = (bf16*)(ws);
  bf16* Pk  = (bf16*)(ws + (1u<<19));
  bf16* wvL = (bf16*)(ws + (2u<<19));
  bf16* vL  = (bf16*)(ws + (3u<<19));
  bf16* PvL = (bf16*)(ws + (3u<<19) + (16u<<20));

  k_wv_cvt <<<64,   256, 0, stream>>>(wv, wvL);
  k_v_cvt  <<<2048, 256, 0, stream>>>(v, vL);
  k_proj_qk<<<256,  256, 0, stream>>>(q, k, wq, bq, wk, bk, Pq, Pk);
  k_proj_v <<<2048, 256, 0, stream>>>(wvL, vL, bv, PvL);
  k_attn   <<<512,  512, 0, stream>>>(Pq, Pk, PvL, v, out);
}

// Round 5
// 315.718 us; speedup vs baseline: 1.5042x; 1.0818x over previous
//
#include <hip/hip_runtime.h>
#include <hip/hip_bf16.h>

typedef __bf16 bf16;
typedef __bf16 bf16x8 __attribute__((ext_vector_type(8)));
typedef float f32x16 __attribute__((ext_vector_type(16)));
typedef float f32x4 __attribute__((ext_vector_type(4)));
typedef unsigned int u32x4 __attribute__((ext_vector_type(4)));

#define NB 4
#define NC 512
#define NN 4096

// log2(e) / sqrt(512): exp(s/sqrt(512)) == exp2(s * EXP2_SCALE)
static constexpr float EXP2_SCALE = 0.063763926f;

static __device__ __forceinline__ unsigned pack_bf2(float a, float b){
  unsigned short ux = __builtin_bit_cast(unsigned short, (bf16)a);
  unsigned short uy = __builtin_bit_cast(unsigned short, (bf16)b);
  return (unsigned)ux | ((unsigned)uy << 16);
}

union FragU { unsigned u[4]; bf16x8 v; };

static __device__ __forceinline__ f32x16 zero16(){
  f32x16 z;
#pragma unroll
  for(int i=0;i<16;i++) z[i] = 0.0f;
  return z;
}

// ---- K1a: wv [512][512] f32 -> wvL[cin/16][co][cin%16] bf16 (A-frag layout)
__global__ __launch_bounds__(256) void k_wv_cvt(const float* __restrict__ wv,
                                                bf16* __restrict__ wvL){
  int t  = blockIdx.x * 256 + threadIdx.x;   // 16384 threads
  int cg = t & 31;
  int co = t >> 5;
  const float* s = wv + (size_t)co * NC + cg * 16;
  unsigned w[8];
#pragma unroll
  for(int j=0;j<8;j++) w[j] = pack_bf2(s[2*j], s[2*j+1]);
  u32x4* d = (u32x4*)((char*)wvL + (size_t)(cg * NC + co) * 32);
  d[0] = (u32x4){w[0],w[1],w[2],w[3]};
  d[1] = (u32x4){w[4],w[5],w[6],w[7]};
}

// ---- K1b: v [B][C][N] f32 -> vL[b][c/16][n][c%16] bf16 (B-frag layout)
__global__ __launch_bounds__(256) void k_v_cvt(const float* __restrict__ v,
                                               bf16* __restrict__ vL){
  int bid = blockIdx.x;            // 2048 = B*32*16
  int n  = (bid & 15) * 256 + threadIdx.x;
  int cg = (bid >> 4) & 31;
  int b  = bid >> 9;
  const float* s = v + ((size_t)(b * NC + cg * 16)) * NN + n;
  unsigned w[8];
#pragma unroll
  for(int j=0;j<8;j++) w[j] = pack_bf2(s[(size_t)(2*j)*NN], s[(size_t)(2*j+1)*NN]);
  u32x4* d = (u32x4*)((char*)vL + ((size_t)(b*32 + cg) * NN + n) * 32);
  d[0] = (u32x4){w[0],w[1],w[2],w[3]};
  d[1] = (u32x4){w[4],w[5],w[6],w[7]};
}

// ---- K2 v2: q,k projections -> Pq, Pk bf16 [B][N][16]
// 8 waves: waves 0-3 -> q (c-chunks of 128), waves 4-7 -> k. Unroll-4 for
// load pipelining (4 coalesced loads in flight). 4-way LDS reduce.
__global__ __launch_bounds__(512) void k_proj_qk(
    const float* __restrict__ q, const float* __restrict__ kin,
    const float* __restrict__ wq, const float* __restrict__ bq,
    const float* __restrict__ wk, const float* __restrict__ bk,
    bf16* __restrict__ Pq, bf16* __restrict__ Pk){
  __shared__ float red[8][64][20];           // +pad: spreads banks
  int b  = blockIdx.x >> 6;
  int n0 = (blockIdx.x & 63) * 64;
  int w  = threadIdx.x >> 6;                 // 0..7
  int lane = threadIdx.x & 63;
  int isk = w >> 2;
  const float* src = isk ? kin : q;
  const float* wt  = isk ? wk : wq;
  int c0 = (w & 3) * 128;
  float acc[16];
#pragma unroll
  for(int o=0;o<16;o++) acc[o] = 0.0f;
  const float* sp = src + ((size_t)(b * NC + c0)) * NN + n0 + lane;
#pragma unroll 4
  for(int c=0;c<128;c++){
    float x = sp[(size_t)c * NN];            // coalesced across lanes
#pragma unroll
    for(int o=0;o<16;o++) acc[o] += wt[o * NC + c0 + c] * x;  // uniform -> s_load
  }
#pragma unroll
  for(int o4=0;o4<4;o4++)
    *(f32x4*)&red[w][lane][o4*4] = (f32x4){acc[o4*4],acc[o4*4+1],acc[o4*4+2],acc[o4*4+3]};
  __syncthreads();
  if(threadIdx.x < 128){
    int wk2 = threadIdx.x >> 6;              // 0 -> q, 1 -> k
    int tok = threadIdx.x & 63;
    const float* bias = wk2 ? bk : bq;
    bf16* dst = wk2 ? Pk : Pq;
    int wb = wk2 * 4;
    unsigned wd[8];
#pragma unroll
    for(int t=0;t<8;t++){
      float a0 = bias[2*t],  a1 = bias[2*t+1];
#pragma unroll
      for(int ww=0;ww<4;ww++){
        a0 += red[wb+ww][tok][2*t];
        a1 += red[wb+ww][tok][2*t+1];
      }
      wd[t] = pack_bf2(a0, a1);
    }
    u32x4* d = (u32x4*)((char*)dst + ((size_t)(b * NN + n0 + tok)) * 32);
    d[0] = (u32x4){wd[0],wd[1],wd[2],wd[3]};
    d[1] = (u32x4){wd[4],wd[5],wd[6],wd[7]};
  }
}

// ---- K3: proj_v GEMM (bf16 MFMA): Pv = wv @ v + bv -> PvL[b][j/16][c][j%16]
__global__ __launch_bounds__(256) void k_proj_v(
    const bf16* __restrict__ wvL, const bf16* __restrict__ vL,
    const float* __restrict__ bv, bf16* __restrict__ PvL){
  int bid = blockIdx.x;                 // 2048 = B * 8 * 64
  int nt  = bid & 63;
  int cot = (bid >> 6) & 7;
  int b   = bid >> 9;
  int w    = threadIdx.x >> 6;
  int lane = threadIdx.x & 63;
  int l31 = lane & 31, h = lane >> 5;
  int co0 = cot * 64 + (w >> 1) * 32;
  int n0  = nt * 64 + (w & 1) * 32;
  const char* ap = (const char*)wvL + (size_t)(co0 + l31) * 32 + h * 16;
  const char* bp = (const char*)vL + ((size_t)(b * 32) * NN + n0 + l31) * 32 + h * 16;
  f32x16 acc = zero16();
  for(int kc=0;kc<32;kc++){
    bf16x8 af  = *(const bf16x8*)(ap + (size_t)kc * NC * 32);
    bf16x8 bfr = *(const bf16x8*)(bp + (size_t)kc * NN * 32);
    acc = __builtin_amdgcn_mfma_f32_32x32x16_bf16(af, bfr, acc, 0, 0, 0);
  }
  int j = n0 + l31;
  char* dbase = (char*)PvL + ((size_t)(b*256 + (j >> 4)) * NC) * 32 + (j & 15) * 2;
#pragma unroll
  for(int r=0;r<16;r++){
    int row = (r & 3) + 8 * (r >> 2) + 4 * h;   // C/D layout (m74/m101)
    int co = co0 + row;
    float val = acc[r] + bv[co];
    *(bf16*)(dbase + (size_t)co * 32) = (bf16)val;
  }
}

// ---- K4 v3: j-parallel shared-P flash attention.
// + chunk-XOR LDS swizzle (conflict-free b128), XCD-affine block mapping
// (each batch pinned to 2 XCDs so its 4MB Pv lives in one L2), kf prefetch.
__global__ __launch_bounds__(512, 4) void k_attn(
    const bf16* __restrict__ Pq, const bf16* __restrict__ Pk,
    const bf16* __restrict__ PvL, const float* __restrict__ vin,
    float* __restrict__ out){
  __shared__ __attribute__((aligned(16))) unsigned P_lds[2][8][64][8]; // [dbuf][jt][lane][word]
  __shared__ float lsum_lds[8][64];
  // XCD-affine decode: xcd = blk&7 (round-robin dispatch), batch = xcd>>1.
  // Bijective: blk = ((itile>>1)<<3) | (2b | (itile&1)).
  int blk  = blockIdx.x;
  int xcd  = blk & 7;
  int b    = xcd >> 1;
  int itile= ((blk >> 3) << 1) | (xcd & 1);
  int i0 = itile * 32;
  int w    = threadIdx.x >> 6;
  int lane = threadIdx.x & 63;
  int l31 = lane & 31, h = lane >> 5;
  int c0 = w * 64;                       // this wave's channel chunk (phase 2)
  int sw4 = ((lane >> 2) & 1) * 4;       // chunk swizzle (in u32 units)

  bf16x8 qf = *(const bf16x8*)((const char*)Pq + ((size_t)(b * NN + i0 + l31)) * 32 + h * 16);

  f32x16 acc0 = zero16(), acc1 = zero16();
  float lsum = 0.0f;

  const char* pkbase = (const char*)Pk  + ((size_t)b * NN) * 32 + h * 16;
  const char* pvbase = (const char*)PvL + ((size_t)(b * 256) * NC) * 32 + h * 16;

  // prefetch first K fragment (this wave's jt of J=0)
  bf16x8 kf = *(const bf16x8*)(pkbase + (size_t)(w * 32 + l31) * 32);

  for(int J=0;J<16;J++){
    int buf = J & 1;
    // ---- phase 1: this wave's jt = J*8 + w -> P A-frags to LDS (swizzled)
    {
      f32x16 s = __builtin_amdgcn_mfma_f32_32x32x16_bf16(kf, qf, zero16(), 0, 0, 0);
      if(J < 15)   // prefetch next J's K frag; latency hides under phase 2
        kf = *(const bf16x8*)(pkbase + (size_t)((J+1)*8*32 + w*32 + l31) * 32);
      float p[16];
#pragma unroll
      for(int r=0;r<16;r++){ p[r] = exp2f(s[r] * EXP2_SCALE); lsum += p[r]; }
      unsigned qw[8], ew[8];
#pragma unroll
      for(int t=0;t<8;t++) qw[t] = pack_bf2(p[2*t], p[2*t+1]);
#pragma unroll
      for(int t=0;t<8;t++) ew[t] = (unsigned)__shfl_xor((int)qw[t], 32);
      u32x4 pa0 = h ? (u32x4){ew[2],ew[3],qw[2],qw[3]} : (u32x4){qw[0],qw[1],ew[0],ew[1]};
      u32x4 pa1 = h ? (u32x4){ew[6],ew[7],qw[6],qw[7]} : (u32x4){qw[4],qw[5],ew[4],ew[5]};
      unsigned* row = &P_lds[buf][w][lane][0];
      *(u32x4*)(row + sw4)       = pa0;   // chunk 0^sw
      *(u32x4*)(row + (4 - sw4)) = pa1;   // chunk 1^sw
    }
    __syncthreads();
    // ---- phase 2: PV over the 8 shared jt tiles, this wave's 64 channels
#pragma unroll
    for(int t=0;t<8;t++){
      FragU pa0, pa1;
      const unsigned* row = &P_lds[buf][t][lane][0];
      *(u32x4*)pa0.u = *(const u32x4*)(row + sw4);
      *(u32x4*)pa1.u = *(const u32x4*)(row + (4 - sw4));
      const char* pvp = pvbase + (((size_t)(J*8 + t) * 2) * NC + c0 + l31) * 32;
      bf16x8 v00 = *(const bf16x8*)(pvp);                         // kstep0, csub0
      bf16x8 v10 = *(const bf16x8*)(pvp + (size_t)NC * 32);       // kstep1, csub0
      bf16x8 v01 = *(const bf16x8*)(pvp + 1024);                  // kstep0, csub1
      bf16x8 v11 = *(const bf16x8*)(pvp + (size_t)NC * 32 + 1024);// kstep1, csub1
      acc0 = __builtin_amdgcn_mfma_f32_32x32x16_bf16(pa0.v, v00, acc0, 0, 0, 0);
      acc0 = __builtin_amdgcn_mfma_f32_32x32x16_bf16(pa1.v, v10, acc0, 0, 0, 0);
      acc1 = __builtin_amdgcn_mfma_f32_32x32x16_bf16(pa0.v, v01, acc1, 0, 0, 0);
      acc1 = __builtin_amdgcn_mfma_f32_32x32x16_bf16(pa1.v, v11, acc1, 0, 0, 0);
    }
  }
  // ---- denominator: cross-wave reduce (no-max softmax is plain summation)
  lsum_lds[w][lane] = lsum;
  __syncthreads();
  float rowsum = 0.0f;
#pragma unroll
  for(int ww=0;ww<8;ww++) rowsum += lsum_lds[ww][l31] + lsum_lds[ww][l31 + 32];
  float rl = 1.0f / rowsum;
  float rlr[16];
#pragma unroll
  for(int r=0;r<16;r++) rlr[r] = __shfl(rl, (r & 3) + 8 * (r >> 2) + 4 * h);
  // ---- epilogue: out[b][c][i] = acc/l + v
#pragma unroll
  for(int cs=0;cs<2;cs++){
    f32x16 a = cs ? acc1 : acc0;
    int c = c0 + cs * 32 + l31;
    const float* vp = vin + ((size_t)(b * NC + c)) * NN + i0;
    float* op = out + ((size_t)(b * NC + c)) * NN + i0;
#pragma unroll
    for(int g=0;g<4;g++){
      int ib = 8 * g + 4 * h;
      f32x4 vv = *(const f32x4*)(vp + ib);
      f32x4 ov;
#pragma unroll
      for(int e=0;e<4;e++) ov[e] = a[4*g+e] * rlr[4*g+e] + vv[e];
      *(f32x4*)(op + ib) = ov;
    }
  }
}

extern "C" void kernel_launch(void* const* d_in, const int* in_sizes, int n_in,
                              void* d_out, int out_size, void* d_ws, size_t ws_size,
                              hipStream_t stream) {
  const float* q  = (const float*)d_in[0];
  const float* k  = (const float*)d_in[1];
  const float* v  = (const float*)d_in[2];
  const float* wq = (const float*)d_in[3];
  const float* bq = (const float*)d_in[4];
  const float* wk = (const float*)d_in[5];
  const float* bk = (const float*)d_in[6];
  const float* wv = (const float*)d_in[7];
  const float* bv = (const float*)d_in[8];
  float* out = (float*)d_out;
  char* ws = (char*)d_ws;

  // workspace layout (bytes): Pq 512K | Pk 512K | wvL 512K | vL 16M | PvL 16M
  bf16* Pq  = (bf16*)(ws);
  bf16* Pk  = (bf16*)(ws + (1u<<19));
  bf16* wvL = (bf16*)(ws + (2u<<19));
  bf16* vL  = (bf16*)(ws + (3u<<19));
  bf16* PvL = (bf16*)(ws + (3u<<19) + (16u<<20));

  k_wv_cvt <<<64,   256, 0, stream>>>(wv, wvL);
  k_v_cvt  <<<2048, 256, 0, stream>>>(v, vL);
  k_proj_qk<<<256,  512, 0, stream>>>(q, k, wq, bq, wk, bk, Pq, Pk);
  k_proj_v <<<2048, 256, 0, stream>>>(wvL, vL, bv, PvL);
  k_attn   <<<512,  512, 0, stream>>>(Pq, Pk, PvL, v, out);
}

// Round 11
// 309.660 us; speedup vs baseline: 1.5336x; 1.0196x over previous
//
#include <hip/hip_runtime.h>
#include <hip/hip_bf16.h>

typedef __bf16 bf16;
typedef __bf16 bf16x8 __attribute__((ext_vector_type(8)));
typedef float f32x16 __attribute__((ext_vector_type(16)));
typedef float f32x4 __attribute__((ext_vector_type(4)));
typedef unsigned int u32x4 __attribute__((ext_vector_type(4)));

#define NB 4
#define NC 512
#define NN 4096

// log2(e) / sqrt(512): exp(s/sqrt(512)) == exp2(s * EXP2_SCALE)
static constexpr float EXP2_SCALE = 0.063763926f;

static __device__ __forceinline__ unsigned pack_bf2(float a, float b){
  unsigned short ux = __builtin_bit_cast(unsigned short, (bf16)a);
  unsigned short uy = __builtin_bit_cast(unsigned short, (bf16)b);
  return (unsigned)ux | ((unsigned)uy << 16);
}

union FragU { unsigned u[4]; bf16x8 v; };

static __device__ __forceinline__ f32x16 zero16(){
  f32x16 z;
#pragma unroll
  for(int i=0;i<16;i++) z[i] = 0.0f;
  return z;
}

// ---- K1a: wv [512][512] f32 -> wvL[cin/16][co][cin%16] bf16 (A-frag layout)
__global__ __launch_bounds__(256) void k_wv_cvt(const float* __restrict__ wv,
                                                bf16* __restrict__ wvL){
  int t  = blockIdx.x * 256 + threadIdx.x;   // 16384 threads
  int cg = t & 31;
  int co = t >> 5;
  const float* s = wv + (size_t)co * NC + cg * 16;
  unsigned w[8];
#pragma unroll
  for(int j=0;j<8;j++) w[j] = pack_bf2(s[2*j], s[2*j+1]);
  u32x4* d = (u32x4*)((char*)wvL + (size_t)(cg * NC + co) * 32);
  d[0] = (u32x4){w[0],w[1],w[2],w[3]};
  d[1] = (u32x4){w[4],w[5],w[6],w[7]};
}

// ---- K1b: v [B][C][N] f32 -> vL[b][c/16][n][c%16] bf16 (B-frag layout)
__global__ __launch_bounds__(256) void k_v_cvt(const float* __restrict__ v,
                                               bf16* __restrict__ vL){
  int bid = blockIdx.x;            // 2048 = B*32*16
  int n  = (bid & 15) * 256 + threadIdx.x;
  int cg = (bid >> 4) & 31;
  int b  = bid >> 9;
  const float* s = v + ((size_t)(b * NC + cg * 16)) * NN + n;
  unsigned w[8];
#pragma unroll
  for(int j=0;j<8;j++) w[j] = pack_bf2(s[(size_t)(2*j)*NN], s[(size_t)(2*j+1)*NN]);
  u32x4* d = (u32x4*)((char*)vL + ((size_t)(b*32 + cg) * NN + n) * 32);
  d[0] = (u32x4){w[0],w[1],w[2],w[3]};
  d[1] = (u32x4){w[4],w[5],w[6],w[7]};
}

// ---- K2 v3: q,k projections -> Pq (pre-scaled by EXP2_SCALE), Pk bf16 [B][N][16]
__global__ __launch_bounds__(512) void k_proj_qk(
    const float* __restrict__ q, const float* __restrict__ kin,
    const float* __restrict__ wq, const float* __restrict__ bq,
    const float* __restrict__ wk, const float* __restrict__ bk,
    bf16* __restrict__ Pq, bf16* __restrict__ Pk){
  __shared__ float red[8][64][20];           // +pad: spreads banks
  int b  = blockIdx.x >> 6;
  int n0 = (blockIdx.x & 63) * 64;
  int w  = threadIdx.x >> 6;                 // 0..7
  int lane = threadIdx.x & 63;
  int isk = w >> 2;
  const float* src = isk ? kin : q;
  const float* wt  = isk ? wk : wq;
  int c0 = (w & 3) * 128;
  float acc[16];
#pragma unroll
  for(int o=0;o<16;o++) acc[o] = 0.0f;
  const float* sp = src + ((size_t)(b * NC + c0)) * NN + n0 + lane;
#pragma unroll 4
  for(int c=0;c<128;c++){
    float x = sp[(size_t)c * NN];            // coalesced across lanes
#pragma unroll
    for(int o=0;o<16;o++) acc[o] += wt[o * NC + c0 + c] * x;  // uniform -> s_load
  }
#pragma unroll
  for(int o4=0;o4<4;o4++)
    *(f32x4*)&red[w][lane][o4*4] = (f32x4){acc[o4*4],acc[o4*4+1],acc[o4*4+2],acc[o4*4+3]};
  __syncthreads();
  if(threadIdx.x < 128){
    int wk2 = threadIdx.x >> 6;              // 0 -> q, 1 -> k
    int tok = threadIdx.x & 63;
    const float* bias = wk2 ? bk : bq;
    bf16* dst = wk2 ? Pk : Pq;
    float sc = wk2 ? 1.0f : EXP2_SCALE;      // fold softmax scale into Pq
    int wb = wk2 * 4;
    unsigned wd[8];
#pragma unroll
    for(int t=0;t<8;t++){
      float a0 = bias[2*t],  a1 = bias[2*t+1];
#pragma unroll
      for(int ww=0;ww<4;ww++){
        a0 += red[wb+ww][tok][2*t];
        a1 += red[wb+ww][tok][2*t+1];
      }
      wd[t] = pack_bf2(a0 * sc, a1 * sc);
    }
    u32x4* d = (u32x4*)((char*)dst + ((size_t)(b * NN + n0 + tok)) * 32);
    d[0] = (u32x4){wd[0],wd[1],wd[2],wd[3]};
    d[1] = (u32x4){wd[4],wd[5],wd[6],wd[7]};
  }
}

// ---- K3 v2: proj_v GEMM -> PvL[b][j/16][c][j%16], LDS-transpose epilogue
// (replaces 16 scattered 2B global stores/lane with 2 coalesced b128 stores)
__global__ __launch_bounds__(256) void k_proj_v(
    const bf16* __restrict__ wvL, const bf16* __restrict__ vL,
    const float* __restrict__ bv, bf16* __restrict__ PvL){
  __shared__ float stg[4][2][33][17];   // [wave][jg][cloc pad][jloc pad]
  int bid = blockIdx.x;                 // 2048 = B * 8 * 64
  int nt  = bid & 63;
  int cot = (bid >> 6) & 7;
  int b   = bid >> 9;
  int w    = threadIdx.x >> 6;
  int lane = threadIdx.x & 63;
  int l31 = lane & 31, h = lane >> 5;
  int co0 = cot * 64 + (w >> 1) * 32;
  int n0  = nt * 64 + (w & 1) * 32;
  const char* ap = (const char*)wvL + (size_t)(co0 + l31) * 32 + h * 16;
  const char* bp = (const char*)vL + ((size_t)(b * 32) * NN + n0 + l31) * 32 + h * 16;
  f32x16 acc = zero16();
  for(int kc=0;kc<32;kc++){
    bf16x8 af  = *(const bf16x8*)(ap + (size_t)kc * NC * 32);
    bf16x8 bfr = *(const bf16x8*)(bp + (size_t)kc * NN * 32);
    acc = __builtin_amdgcn_mfma_f32_32x32x16_bf16(af, bfr, acc, 0, 0, 0);
  }
  // transpose via LDS: writer lane owns (j = n0+l31, co = co0+row)
#pragma unroll
  for(int r=0;r<16;r++){
    int row = (r & 3) + 8 * (r >> 2) + 4 * h;   // C/D layout (m74/m101)
    stg[w][l31 >> 4][row][l31 & 15] = acc[r] + bv[co0 + row];
  }
  // reader lane: (jg = lane>>5, cloc = l31) -> one 32B [c][j%16] row
  // same-wave LDS write->read: DS pipe is in-order per wave; compiler adds lgkm waits
  const float* rp = &stg[w][lane >> 5][l31][0];
  unsigned wd[8];
#pragma unroll
  for(int jl=0;jl<8;jl++) wd[jl] = pack_bf2(rp[2*jl], rp[2*jl+1]);
  char* gb = (char*)PvL + (((size_t)(b*256 + (n0 >> 4) + (lane >> 5))) * NC + co0 + l31) * 32;
  *(u32x4*)gb        = (u32x4){wd[0],wd[1],wd[2],wd[3]};
  *(u32x4*)(gb + 16) = (u32x4){wd[4],wd[5],wd[6],wd[7]};
}

// ---- K4 v4: j-parallel shared-P flash attention.
// permlane32_swap (no bpermute; shfl_xor fallback if builtin absent), raw
// s_barrier + lgkmcnt-only wait (pv loads stay in flight across barriers),
// depth-2 rolling pv register prefetch, setprio around MFMA cluster.
__global__ __launch_bounds__(512, 4) void k_attn(
    const bf16* __restrict__ Pq, const bf16* __restrict__ Pk,
    const bf16* __restrict__ PvL, const float* __restrict__ vin,
    float* __restrict__ out){
  __shared__ __attribute__((aligned(16))) unsigned P_lds[2][8][64][8]; // [dbuf][jt][lane][word]
  __shared__ float lsum_lds[8][64];
  // XCD-affine decode: xcd = blk&7 (round-robin dispatch), batch = xcd>>1.
  int blk  = blockIdx.x;
  int xcd  = blk & 7;
  int b    = xcd >> 1;
  int itile= ((blk >> 3) << 1) | (xcd & 1);
  int i0 = itile * 32;
  int w    = threadIdx.x >> 6;
  int lane = threadIdx.x & 63;
  int l31 = lane & 31, h = lane >> 5;
  int c0 = w * 64;                       // this wave's channel chunk (phase 2)
  int sw4 = ((lane >> 2) & 1) * 4;       // chunk swizzle (in u32 units)

  bf16x8 qf = *(const bf16x8*)((const char*)Pq + ((size_t)(b * NN + i0 + l31)) * 32 + h * 16);

  f32x16 acc0 = zero16(), acc1 = zero16();
  f32x4 lsv = (f32x4){0.f, 0.f, 0.f, 0.f};

  const char* pkbase = (const char*)Pk  + ((size_t)b * NN) * 32 + h * 16;
  const char* pvbase = (const char*)PvL + ((size_t)(b * 256) * NC) * 32 + h * 16;

#define PVP(T) (pvbase + ((size_t)(T) * 2 * NC + c0 + l31) * 32)
  // prologue: prefetch pv tiles T=0,1 and first K fragment
  bf16x8 vb[2][4];
#pragma unroll
  for(int s0=0;s0<2;s0++){
    const char* p0 = PVP(s0);
    vb[s0][0] = *(const bf16x8*)(p0);
    vb[s0][1] = *(const bf16x8*)(p0 + (size_t)NC * 32);
    vb[s0][2] = *(const bf16x8*)(p0 + 1024);
    vb[s0][3] = *(const bf16x8*)(p0 + (size_t)NC * 32 + 1024);
  }
  bf16x8 kf = *(const bf16x8*)(pkbase + (size_t)(w * 32 + l31) * 32);

  for(int J=0;J<16;J++){
    int buf = J & 1;
    // ---- phase 1: this wave's jt = J*8 + w -> P A-frags to LDS (swizzled)
    {
      f32x16 s = __builtin_amdgcn_mfma_f32_32x32x16_bf16(kf, qf, zero16(), 0, 0, 0);
      if(J < 15)
        kf = *(const bf16x8*)(pkbase + (size_t)((J+1)*8*32 + w*32 + l31) * 32);
      float p[16];
#pragma unroll
      for(int r=0;r<16;r++){ p[r] = exp2f(s[r]); lsv[r & 3] += p[r]; }
      unsigned qw[8];
#pragma unroll
      for(int t=0;t<8;t++) qw[t] = pack_bf2(p[2*t], p[2*t+1]);
      u32x4 pa0, pa1;
#if __has_builtin(__builtin_amdgcn_permlane32_swap)
      // lane<32 / lane>=32 half exchange: ret0 = {a.lo, b.lo}, ret1 = {a.hi, b.hi}
      auto r0 = __builtin_amdgcn_permlane32_swap(qw[0], qw[2], false, false);
      auto r1 = __builtin_amdgcn_permlane32_swap(qw[1], qw[3], false, false);
      auto r2 = __builtin_amdgcn_permlane32_swap(qw[4], qw[6], false, false);
      auto r3 = __builtin_amdgcn_permlane32_swap(qw[5], qw[7], false, false);
      pa0 = (u32x4){(unsigned)r0[0], (unsigned)r1[0], (unsigned)r0[1], (unsigned)r1[1]};
      pa1 = (u32x4){(unsigned)r2[0], (unsigned)r3[0], (unsigned)r2[1], (unsigned)r3[1]};
#else
      // fallback (run-verified rounds 3-5): explicit half exchange via shfl_xor
      unsigned ew[8];
#pragma unroll
      for(int t=0;t<8;t++) ew[t] = (unsigned)__shfl_xor((int)qw[t], 32);
      pa0 = h ? (u32x4){ew[2],ew[3],qw[2],qw[3]} : (u32x4){qw[0],qw[1],ew[0],ew[1]};
      pa1 = h ? (u32x4){ew[6],ew[7],qw[6],qw[7]} : (u32x4){qw[4],qw[5],ew[4],ew[5]};
#endif
      unsigned* row = &P_lds[buf][w][lane][0];
      *(u32x4*)(row + sw4)       = pa0;
      *(u32x4*)(row + (4 - sw4)) = pa1;
    }
    // LDS-visibility only; pv register loads stay in flight across the barrier
    asm volatile("s_waitcnt lgkmcnt(0)" ::: "memory");
    __builtin_amdgcn_s_barrier();
    asm volatile("" ::: "memory");
    // ---- phase 2: PV over the 8 shared jt tiles, this wave's 64 channels
#pragma unroll
    for(int t=0;t<8;t++){
      FragU pa0, pa1;
      const unsigned* row = &P_lds[buf][t][lane][0];
      *(u32x4*)pa0.u = *(const u32x4*)(row + sw4);
      *(u32x4*)pa1.u = *(const u32x4*)(row + (4 - sw4));
      __builtin_amdgcn_s_setprio(1);
      acc0 = __builtin_amdgcn_mfma_f32_32x32x16_bf16(pa0.v, vb[t & 1][0], acc0, 0, 0, 0);
      acc0 = __builtin_amdgcn_mfma_f32_32x32x16_bf16(pa1.v, vb[t & 1][1], acc0, 0, 0, 0);
      acc1 = __builtin_amdgcn_mfma_f32_32x32x16_bf16(pa0.v, vb[t & 1][2], acc1, 0, 0, 0);
      acc1 = __builtin_amdgcn_mfma_f32_32x32x16_bf16(pa1.v, vb[t & 1][3], acc1, 0, 0, 0);
      __builtin_amdgcn_s_setprio(0);
      // rolling prefetch: reload this slot with tile T+2 (clamped at end)
      int Tn = J * 8 + t + 2; if(Tn > 127) Tn = 127;
      const char* pn = PVP(Tn);
      vb[t & 1][0] = *(const bf16x8*)(pn);
      vb[t & 1][1] = *(const bf16x8*)(pn + (size_t)NC * 32);
      vb[t & 1][2] = *(const bf16x8*)(pn + 1024);
      vb[t & 1][3] = *(const bf16x8*)(pn + (size_t)NC * 32 + 1024);
    }
  }
#undef PVP
  // ---- denominator: cross-wave reduce (no-max softmax is plain summation)
  float lsum = (lsv[0] + lsv[1]) + (lsv[2] + lsv[3]);
  lsum_lds[w][lane] = lsum;
  __syncthreads();
  float rowsum = 0.0f;
#pragma unroll
  for(int ww=0;ww<8;ww++) rowsum += lsum_lds[ww][l31] + lsum_lds[ww][l31 + 32];
  float rl = 1.0f / rowsum;
  float rlr[16];
#pragma unroll
  for(int r=0;r<16;r++) rlr[r] = __shfl(rl, (r & 3) + 8 * (r >> 2) + 4 * h);
  // ---- epilogue: out[b][c][i] = acc/l + v
#pragma unroll
  for(int cs=0;cs<2;cs++){
    f32x16 a = cs ? acc1 : acc0;
    int c = c0 + cs * 32 + l31;
    const float* vp = vin + ((size_t)(b * NC + c)) * NN + i0;
    float* op = out + ((size_t)(b * NC + c)) * NN + i0;
#pragma unroll
    for(int g=0;g<4;g++){
      int ib = 8 * g + 4 * h;
      f32x4 vv = *(const f32x4*)(vp + ib);
      f32x4 ov;
#pragma unroll
      for(int e=0;e<4;e++) ov[e] = a[4*g+e] * rlr[4*g+e] + vv[e];
      *(f32x4*)(op + ib) = ov;
    }
  }
}

extern "C" void kernel_launch(void* const* d_in, const int* in_sizes, int n_in,
                              void* d_out, int out_size, void* d_ws, size_t ws_size,
                              hipStream_t stream) {
  const float* q  = (const float*)d_in[0];
  const float* k  = (const float*)d_in[1];
  const float* v  = (const float*)d_in[2];
  const float* wq = (const float*)d_in[3];
  const float* bq = (const float*)d_in[4];
  const float* wk = (const float*)d_in[5];
  const float* bk = (const float*)d_in[6];
  const float* wv = (const float*)d_in[7];
  const float* bv = (const float*)d_in[8];
  float* out = (float*)d_out;
  char* ws = (char*)d_ws;

  // workspace layout (bytes): Pq 512K | Pk 512K | wvL 512K | vL 16M | PvL 16M
  bf16* Pq  = (bf16*)(ws);
  bf16* Pk  = (bf16*)(ws + (1u<<19));
  bf16* wvL = (bf16*)(ws + (2u<<19));
  bf16* vL  = (bf16*)(ws + (3u<<19));
  bf16* PvL = (bf16*)(ws + (3u<<19) + (16u<<20));

  k_wv_cvt <<<64,   256, 0, stream>>>(wv, wvL);
  k_v_cvt  <<<2048, 256, 0, stream>>>(v, vL);
  k_proj_qk<<<256,  512, 0, stream>>>(q, k, wq, bq, wk, bk, Pq, Pk);
  k_proj_v <<<2048, 256, 0, stream>>>(wvL, vL, bv, PvL);
  k_attn   <<<512,  512, 0, stream>>>(Pq, Pk, PvL, v, out);
}